// Round 5
// baseline (278.905 us; speedup 1.0000x reference)
//
#include <hip/hip_runtime.h>
#include <hip/hip_cooperative_groups.h>
#include <cstdint>

namespace cg = cooperative_groups;

// ATSS matcher — single fused cooperative kernel (1 launch instead of 4).
//  Stage A (all 576 blocks, one 512-anchor range each over levels 0/1):
//    block 9 zeroes cnt[] then publishes a 64-bit MAGIC flag (poison-proof);
//    blocks 0-8 zero packed[] for the level-2/3 tail; every block zeroes
//    packed[] for its own range. Scan: centers in registers, d2<=T gate,
//    per-lane LDS atomic append into per-GT queues (R3-verified: pipelines
//    fine; ballot compaction measured WORSE in R4). Flush: spin on MAGIC
//    (cnt zeroed), then one global atomicAdd per non-empty (block,gt) +
//    serial copy (R3-verified). Overflow -> cnt+=2e6 -> exact fallback, so
//    correctness does NOT depend on T/QCAP.
//  grid.sync()
//  Stage C (blocks 0..m-1, 4 waves = 4 FPN levels): register-resident exact
//    top-9 (9 rounds of wave argmin-with-removal on packed u64 == exact d2
//    order + lowest-index tie-break, matching jax top_k). Waves 0/1 read the
//    filtered lists (<=8 elems/lane; exact full-rescan fallback otherwise).
//    Waves 2/3 ALWAYS direct-scan their 4096/512 anchors (L2-resident; this
//    removes the level-2 scan straggler seen in R3/R4). Then wave 0: fused
//    IoU -> mean+std(ddof=1) threshold -> center-inside -> atomicMax
//    (iou<<32 | ~gt) argmax scatter into packed[].
//  grid.sync()
//  Stage D: decode packed -> (matched_gt, matched_iou, labels) f32.
//
// All arithmetic forms (center=(lo+hi)*0.5f, d2=sa+sg-2*dot, IoU, threshold)
// are byte-identical to the verified R3 kernel so selection order matches.

#define NCAND 36
#define CAP 1024          // global list capacity per (gt,lvl)
#define LISTMAX 512       // max usable list length in stage C (8 per lane)
#define QCAP 64           // per-block per-gt LDS queue capacity
#define LVL2_START 294912
#define LVL3_START 299008
#define SCAN_BLOCKS 576   // 294912 / 512 (levels 0/1; bounds 512-aligned)
#define MAGIC 0x9E3779B97F4A7C15ULL

__device__ __constant__ int   c_lvl_start[2] = {0, 262144};
__device__ __constant__ int   c_lvl_end[2]   = {262144, 294912};
// (3 * r9_bulk)^2 per level; r9_bulk = (9 / (4/3 pi rho))^(1/3), rho = lvl/512^3
__device__ __constant__ float c_T[2] = {961.0f, 3844.0f};

// order-preserving float->uint (handles negative d2 from cancellation)
__device__ inline unsigned f2ord(float f) {
    unsigned u = __float_as_uint(f);
    return (u & 0x80000000u) ? ~u : (u | 0x80000000u);
}

__global__ void fused(const float* __restrict__ anchors, const float* __restrict__ gt_boxes,
                      unsigned long long* __restrict__ lists, unsigned* __restrict__ cnt,
                      unsigned long long* __restrict__ packed,
                      unsigned long long* __restrict__ ready,
                      float* __restrict__ out, int n, int m) {
    cg::grid_group grid = cg::this_grid();
    int b    = blockIdx.x;
    int tid  = threadIdx.x;      // 0..255
    int lane = tid & 63;

    __shared__ float4 gt4[64];
    __shared__ unsigned qcnt[64];
    __shared__ unsigned long long queue[64][QCAP];   // 32 KiB
    __shared__ int scand[NCAND];

    // ---------------- stage A: zero + scan (levels 0/1) + flush ----------------
    int base = b << 9;
    int lvl  = (base >= 262144) ? 1 : 0;
    float T  = c_T[lvl];

    if (b == 9) {
        for (int i = tid; i < 256 * 16; i += 256) cnt[i] = 0;
    }
    if (b < 9) {   // zero packed[] for the level-2/3 tail (4608 entries)
        int s = LVL2_START + (b << 9) + tid;
        if (s < n) packed[s] = 0ULL;
        if (s + 256 < n) packed[s + 256] = 0ULL;
    }
    if (tid < 64) {
        qcnt[tid] = 0;
        if (tid < m) {
            int g = tid;
            float gx = (gt_boxes[g*6+0] + gt_boxes[g*6+2]) * 0.5f;
            float gy = (gt_boxes[g*6+1] + gt_boxes[g*6+3]) * 0.5f;
            float gz = (gt_boxes[g*6+4] + gt_boxes[g*6+5]) * 0.5f;
            float sg = gx*gx + gy*gy + gz*gz;
            gt4[g] = make_float4(gx, gy, gz, sg);
        }
    }
    __syncthreads();   // gt4/qcnt ready; block 9's cnt stores done block-wide
    if (b == 9 && tid == 0) { __threadfence(); atomicExch(ready, MAGIC); }

    float ax[2], ay[2], az[2], sa[2];
    int   ai[2];
    #pragma unroll
    for (int k = 0; k < 2; k++) {
        int a = base + tid + k*256;
        ai[k] = a;
        const float2* r = (const float2*)(anchors + (size_t)a*6);
        float2 p0 = r[0], p1 = r[1], p2 = r[2];  // (x1,y1)(x2,y2)(z1,z2)
        float cx = (p0.x + p1.x) * 0.5f;
        float cy = (p0.y + p1.y) * 0.5f;
        float cz = (p2.x + p2.y) * 0.5f;
        ax[k] = cx; ay[k] = cy; az[k] = cz;
        sa[k] = cx*cx + cy*cy + cz*cz;
        packed[a] = 0ULL;
    }

    for (int g = 0; g < m; g++) {
        float4 gv = gt4[g];
        #pragma unroll
        for (int k = 0; k < 2; k++) {
            float dot = ax[k]*gv.x + ay[k]*gv.y + az[k]*gv.z;
            float d2  = sa[k] + gv.w - 2.0f*dot;   // same algebraic form as reference
            if (d2 <= T) {
                unsigned long long p =
                    ((unsigned long long)f2ord(d2) << 32) | (unsigned)ai[k];
                unsigned idx = atomicAdd(&qcnt[g], 1u);   // LDS atomic (R3-verified)
                if (idx < QCAP) queue[g][idx] = p;
            }
        }
    }
    __syncthreads();

    // wait until cnt[] is zeroed (block 9 publishes MAGIC; usually already set)
    if (tid == 0) { while (atomicAdd(ready, 0ULL) != MAGIC) {} }
    __syncthreads();

    // flush: one global atomic per non-empty (block, gt)  (R3-verified form)
    if (tid < 64) {
        int g = tid;
        unsigned c = qcnt[g];
        if (c > 0) {
            int gidx = g*4 + lvl;
            if (c > QCAP) {
                atomicAdd(&cnt[gidx * 16], 2000000u);  // force fallback rescan
            } else {
                unsigned bs = atomicAdd(&cnt[gidx * 16], c);
                for (unsigned j = 0; j < c; j++) {
                    unsigned s = bs + j;
                    if (s < CAP) lists[(size_t)gidx*CAP + s] = queue[g][j];
                }
            }
        }
    }
    __threadfence();
    grid.sync();

    // ---------------- stage C: select (blocks 0..m-1) ----------------
    if (b < m) {
        int g  = b;
        int wl = tid >> 6;    // wave id == FPN level

        unsigned c = 0;
        if (wl < 2) c = cnt[(g*4 + wl) * 16];   // issue early

        float gx1 = gt_boxes[g*6+0], gy1 = gt_boxes[g*6+1];
        float gx2 = gt_boxes[g*6+2], gy2 = gt_boxes[g*6+3];
        float gz1 = gt_boxes[g*6+4], gz2 = gt_boxes[g*6+5];
        float gx = (gx1+gx2)*0.5f, gy = (gy1+gy2)*0.5f, gz = (gz1+gz2)*0.5f;
        float sg = gx*gx + gy*gy + gz*gz;

        unsigned long long e[9];
        #pragma unroll
        for (int k = 0; k < 9; k++) e[k] = ~0ULL;

        if (wl == 3) {
            // direct: exactly 512 anchors = 8 per lane, all in registers
            #pragma unroll
            for (int j = 0; j < 8; j++) {
                int i = LVL3_START + lane + 64*j;
                if (i < n) {
                    const float2* r = (const float2*)(anchors + (size_t)i*6);
                    float2 p0 = r[0], p1 = r[1], p2 = r[2];
                    float cx = (p0.x + p1.x) * 0.5f;
                    float cy = (p0.y + p1.y) * 0.5f;
                    float cz = (p2.x + p2.y) * 0.5f;
                    float sa2 = cx*cx + cy*cy + cz*cz;
                    float dot = cx*gx + cy*gy + cz*gz;
                    float d2  = sa2 + sg - 2.0f*dot;
                    e[j] = ((unsigned long long)f2ord(d2) << 32) | (unsigned)i;
                }
            }
        } else if (wl == 2) {
            // direct scan of level 2 (4096 anchors, L2-resident), static chain
            for (int i = LVL2_START + lane; i < LVL3_START; i += 64) {
                const float2* r = (const float2*)(anchors + (size_t)i*6);
                float2 p0 = r[0], p1 = r[1], p2 = r[2];
                float cx = (p0.x + p1.x) * 0.5f;
                float cy = (p0.y + p1.y) * 0.5f;
                float cz = (p2.x + p2.y) * 0.5f;
                float sa2 = cx*cx + cy*cy + cz*cz;
                float dot = cx*gx + cy*gy + cz*gz;
                float d2  = sa2 + sg - 2.0f*dot;
                unsigned long long x = ((unsigned long long)f2ord(d2) << 32) | (unsigned)i;
                if (x < e[8]) {
                    #pragma unroll
                    for (int k = 0; k < 9; k++) {     // static-index min/max chain
                        unsigned long long lo = (x < e[k]) ? x : e[k];
                        unsigned long long hi = (x < e[k]) ? e[k] : x;
                        e[k] = lo; x = hi;
                    }
                }
            }
        } else if (c >= 9 && c <= LISTMAX) {
            // normal path: whole filtered list into registers (<=8 per lane)
            size_t off = (size_t)(g*4 + wl) * CAP;
            #pragma unroll
            for (int j = 0; j < 8; j++) {
                unsigned s = (unsigned)lane + 64u*j;
                if (s < c) e[j] = lists[off + s];
            }
        } else {
            // fallback: full exact rescan of level 0/1 (never expected)
            int s0 = c_lvl_start[wl], s1 = c_lvl_end[wl];
            for (int i = s0 + lane; i < s1; i += 64) {
                const float2* r = (const float2*)(anchors + (size_t)i*6);
                float2 p0 = r[0], p1 = r[1], p2 = r[2];
                float cx = (p0.x + p1.x) * 0.5f;
                float cy = (p0.y + p1.y) * 0.5f;
                float cz = (p2.x + p2.y) * 0.5f;
                float sa2 = cx*cx + cy*cy + cz*cz;
                float dot = cx*gx + cy*gy + cz*gz;
                float d2  = sa2 + sg - 2.0f*dot;
                unsigned long long x = ((unsigned long long)f2ord(d2) << 32) | (unsigned)i;
                if (x < e[8]) {
                    #pragma unroll
                    for (int k = 0; k < 9; k++) {
                        unsigned long long lo = (x < e[k]) ? x : e[k];
                        unsigned long long hi = (x < e[k]) ? e[k] : x;
                        e[k] = lo; x = hi;
                    }
                }
            }
        }

        // exact top-9: 9 rounds of wave-wide argmin with removal.
        // packed keys are unique (anchor idx in low bits) -> one removal/round.
        #pragma unroll
        for (int r9 = 0; r9 < 9; r9++) {
            unsigned long long mn = e[0];
            #pragma unroll
            for (int j = 1; j < 9; j++) mn = (e[j] < mn) ? e[j] : mn;
            #pragma unroll
            for (int off = 32; off >= 1; off >>= 1) {
                unsigned long long o = __shfl_xor(mn, off);
                mn = (o < mn) ? o : mn;
            }
            if (lane == 0) scand[wl*9 + r9] = (int)(unsigned)mn;
            #pragma unroll
            for (int j = 0; j < 9; j++) e[j] = (e[j] == mn) ? ~0ULL : e[j];
        }
        __syncthreads();

        if (tid < 64) {
            float vg = (gx2 - gx1) * (gy2 - gy1) * (gz2 - gz1);
            bool valid = (tid < NCAND);
            float iou = 0.0f;
            int aidx = 0;
            float acx = 0.0f, acy = 0.0f, acz = 0.0f;
            if (valid) {
                aidx = scand[tid];
                float ax1 = anchors[aidx*6+0], ay1 = anchors[aidx*6+1];
                float ax2 = anchors[aidx*6+2], ay2 = anchors[aidx*6+3];
                float az1 = anchors[aidx*6+4], az2 = anchors[aidx*6+5];
                float va = (ax2 - ax1) * (ay2 - ay1) * (az2 - az1);
                float wx = fmaxf(fminf(ax2, gx2) - fmaxf(ax1, gx1), 0.0f);
                float wy = fmaxf(fminf(ay2, gy2) - fmaxf(ay1, gy1), 0.0f);
                float wz = fmaxf(fminf(az2, gz2) - fmaxf(az1, gz1), 0.0f);
                float inter = wx * wy * wz;
                iou = inter / (va + vg - inter + 1e-6f);
                acx = (ax1 + ax2) * 0.5f;
                acy = (ay1 + ay2) * 0.5f;
                acz = (az1 + az2) * 0.5f;
            }

            float s = iou;
            #pragma unroll
            for (int o = 32; o >= 1; o >>= 1) s += __shfl_xor(s, o);
            float mean = s / 36.0f;
            float dev = valid ? (iou - mean) : 0.0f;
            float s2 = dev * dev;
            #pragma unroll
            for (int o = 32; o >= 1; o >>= 1) s2 += __shfl_xor(s2, o);
            float thr = fmaxf(mean + sqrtf(s2 / 35.0f), 0.0f);  // MIN_IOU = 0

            if (valid && iou >= thr) {
                bool inside = (acx >= gx1) & (acx <= gx2) &
                              (acy >= gy1) & (acy <= gy2) &
                              (acz >= gz1) & (acz <= gz2);
                if (inside) {
                    unsigned long long p =
                        ((unsigned long long)__float_as_uint(iou) << 32) | (unsigned)(~(unsigned)g);
                    atomicMax(&packed[aidx], p);
                }
            }
        }
    }
    __threadfence();
    grid.sync();

    // ---------------- stage D: decode ----------------
    {
        int i0 = (b << 9) + tid;
        #pragma unroll
        for (int k = 0; k < 2; k++) {
            int i = i0 + k*256;
            if (i < n) {
                unsigned long long p = packed[i];
                float gt_f, iou_f, lab_f;
                if (p == 0ULL) { gt_f = -1.0f; iou_f = 0.0f; lab_f = 0.0f; }
                else {
                    iou_f = __uint_as_float((unsigned)(p >> 32));
                    gt_f  = (float)((int)(~(unsigned)p));
                    lab_f = 1.0f;
                }
                out[i] = gt_f; out[n + i] = iou_f; out[2*n + i] = lab_f;
            }
        }
        if (b < 9) {   // tail chunks: level 2/3 region
            int j0 = LVL2_START + (b << 9) + tid;
            #pragma unroll
            for (int k = 0; k < 2; k++) {
                int i = j0 + k*256;
                if (i < n) {
                    unsigned long long p = packed[i];
                    float gt_f, iou_f, lab_f;
                    if (p == 0ULL) { gt_f = -1.0f; iou_f = 0.0f; lab_f = 0.0f; }
                    else {
                        iou_f = __uint_as_float((unsigned)(p >> 32));
                        gt_f  = (float)((int)(~(unsigned)p));
                        lab_f = 1.0f;
                    }
                    out[i] = gt_f; out[n + i] = iou_f; out[2*n + i] = lab_f;
                }
            }
        }
    }
}

extern "C" void kernel_launch(void* const* d_in, const int* in_sizes, int n_in,
                              void* d_out, int out_size, void* d_ws, size_t ws_size,
                              hipStream_t stream) {
    const float* gt      = (const float*)d_in[0];
    const float* anchors = (const float*)d_in[1];
    int m = in_sizes[0] / 6;   // 64
    int n = in_sizes[1] / 6;   // 299520

    char* ws = (char*)d_ws;
    unsigned long long* packed = (unsigned long long*)ws;                   // n*8
    unsigned long long* lists  = (unsigned long long*)(ws + (size_t)n * 8); // 256*CAP*8
    unsigned* cnt = (unsigned*)(ws + (size_t)n * 8 + (size_t)256*CAP*8);    // 256*64B
    unsigned long long* ready =
        (unsigned long long*)(ws + (size_t)n * 8 + (size_t)256*CAP*8 + 256*64);

    float* out = (float*)d_out;

    void* args[] = { (void*)&anchors, (void*)&gt, (void*)&lists, (void*)&cnt,
                     (void*)&packed, (void*)&ready, (void*)&out, (void*)&n, (void*)&m };
    hipLaunchCooperativeKernel((const void*)fused, dim3(SCAN_BLOCKS), dim3(256),
                               args, 0, stream);
}

// Round 6
// 55.414 us; speedup vs baseline: 5.0331x; 5.0331x over previous
//
#include <hip/hip_runtime.h>
#include <cstdint>

// ATSS matcher, segmented filter-then-select (exact, 3 kernels):
//  scanK (576 blocks x 512 anchors, levels 0/1 only; bounds 512-aligned):
//    zeroes packed[] for its range (blocks 0-8 also zero the lvl-2/3 tail),
//    centers in registers, d2<=T gate -> per-GT LDS-atomic index (R3-verified;
//    ballot compaction measured worse) -> DIRECT store into the block's
//    private segment lists[gt][seg][QCAP]. Per-(gt,seg) counts written
//    UNCONDITIONALLY and non-atomically at the end -> no zero-init kernel,
//    no global atomics, poison-proof. Overflow (>QCAP, Poisson-impossible)
//    sets a flag bit -> selectC exact fallback, so correctness does NOT
//    depend on T or QCAP.
//  selectC (64 blocks, 4 waves = 4 FPN levels): register-resident exact top-9
//    (9 rounds of wave argmin-with-removal on packed u64 == exact d2 order +
//    lowest-index tie-break, matching jax top_k). Waves 0/1: gather the
//    block-segments (8 / 1 per lane), static-index insert chain; full-rescan
//    fallback if total<9 or any segment overflowed. Waves 2/3: direct scan of
//    their 4096/512 anchors (R5-verified path; removes the lvl-2 scan
//    straggler). Wave 0 then: fused IoU -> mean+std(ddof=1) threshold ->
//    center-inside -> atomicMax (iou<<32 | ~gt) argmax scatter.
//  phaseD: decode packed -> (matched_gt, matched_iou, labels) f32.
//
// NOTE (R5 lesson): cooperative grid.sync() costs ~100+ us on MI355X
// (cross-XCD L2 coherence) — kernel boundaries are far cheaper.
// All arithmetic forms (center=(lo+hi)*0.5f, d2=sa+sg-2*dot, IoU, threshold)
// are byte-identical to the verified R3/R5 kernels so selection matches.

#define NCAND 36
#define QCAP 64           // per-(block,gt) segment capacity; E[fill] <= 3.8
#define OVF  0x80000000u
#define LVL1_START 262144
#define LVL2_START 294912
#define LVL3_START 299008
#define SEG0 512          // level-0 segments (blocks 0..511)
#define SEG1 64           // level-1 segments (blocks 512..575)

__device__ __constant__ int   c_lvl_start[2] = {0, 262144};
__device__ __constant__ int   c_lvl_end[2]   = {262144, 294912};
// (3 * r9_bulk)^2 per level; r9_bulk = (9 / (4/3 pi rho))^(1/3), rho = lvl/512^3
__device__ __constant__ float c_T[2] = {961.0f, 3844.0f};

// order-preserving float->uint (handles negative d2 from cancellation)
__device__ inline unsigned f2ord(float f) {
    unsigned u = __float_as_uint(f);
    return (u & 0x80000000u) ? ~u : (u | 0x80000000u);
}

// one block per 512-anchor range, levels 0/1. 2 anchors/thread in regs,
// all m GTs from LDS. Direct segmented stores; non-atomic count publish.
__global__ void scanK(const float* __restrict__ anchors, const float* __restrict__ gt_boxes,
                      unsigned long long* __restrict__ l0, unsigned long long* __restrict__ l1,
                      unsigned* __restrict__ c0, unsigned* __restrict__ c1,
                      unsigned long long* __restrict__ packed, int n, int m) {
    int b    = blockIdx.x;
    int tid  = threadIdx.x;
    int base = b << 9;
    int lvl  = (base >= LVL1_START) ? 1 : 0;
    float T  = c_T[lvl];

    int segN = (lvl == 0) ? SEG0 : SEG1;
    int seg  = (lvl == 0) ? b : (b - SEG0);
    unsigned long long* lseg = (lvl == 0) ? l0 : l1;

    __shared__ float4 gt4[64];
    __shared__ unsigned qcnt[64];

    if (tid < 64) {
        qcnt[tid] = 0;
        if (tid < m) {
            int g = tid;
            float gx = (gt_boxes[g*6+0] + gt_boxes[g*6+2]) * 0.5f;
            float gy = (gt_boxes[g*6+1] + gt_boxes[g*6+3]) * 0.5f;
            float gz = (gt_boxes[g*6+4] + gt_boxes[g*6+5]) * 0.5f;
            float sg = gx*gx + gy*gy + gz*gz;
            gt4[g] = make_float4(gx, gy, gz, sg);
        }
    }
    if (b < 9) {   // zero packed[] for the level-2/3 tail (4608 entries)
        int s = LVL2_START + (b << 9) + tid;
        if (s < n) packed[s] = 0ULL;
        if (s + 256 < n) packed[s + 256] = 0ULL;
    }
    __syncthreads();

    float ax[2], ay[2], az[2], sa[2];
    int   ai[2];
    #pragma unroll
    for (int k = 0; k < 2; k++) {
        int a = base + tid + k*256;
        ai[k] = a;
        const float2* r = (const float2*)(anchors + (size_t)a*6);
        float2 p0 = r[0], p1 = r[1], p2 = r[2];  // (x1,y1)(x2,y2)(z1,z2)
        float cx = (p0.x + p1.x) * 0.5f;
        float cy = (p0.y + p1.y) * 0.5f;
        float cz = (p2.x + p2.y) * 0.5f;
        ax[k] = cx; ay[k] = cy; az[k] = cz;
        sa[k] = cx*cx + cy*cy + cz*cz;
        packed[a] = 0ULL;
    }

    for (int g = 0; g < m; g++) {
        float4 gv = gt4[g];
        size_t segoff = ((size_t)g * segN + seg) * QCAP;
        #pragma unroll
        for (int k = 0; k < 2; k++) {
            float dot = ax[k]*gv.x + ay[k]*gv.y + az[k]*gv.z;
            float d2  = sa[k] + gv.w - 2.0f*dot;   // same algebraic form as reference
            if (d2 <= T) {
                unsigned idx = atomicAdd(&qcnt[g], 1u);   // LDS atomic (R3-verified)
                if (idx < QCAP) {
                    unsigned long long p =
                        ((unsigned long long)f2ord(d2) << 32) | (unsigned)ai[k];
                    lseg[segoff + idx] = p;   // fire-and-forget 8B store
                }
            }
        }
    }
    __syncthreads();

    // publish counts: unconditional, non-atomic (no zero-init needed anywhere)
    if (tid < 64) {
        unsigned c = qcnt[tid];
        unsigned cw = (c > QCAP) ? OVF : c;
        if (lvl == 0) c0[tid * SEG0 + seg] = cw;
        else          c1[tid * SEG1 + seg] = cw;
    }
}

// one block (256 threads = 4 waves) per GT; wave w handles FPN level w.
// All candidate state in named registers (static indexing only).
__global__ void selectC(const unsigned long long* __restrict__ l0,
                        const unsigned long long* __restrict__ l1,
                        const unsigned* __restrict__ c0,
                        const unsigned* __restrict__ c1,
                        const float* __restrict__ anchors,
                        const float* __restrict__ gt_boxes,
                        unsigned long long* __restrict__ packed, int n) {
    int g = blockIdx.x;
    int tid = threadIdx.x;     // 0..255
    int wl  = tid >> 6;        // wave id == level
    int lane = tid & 63;
    __shared__ int scand[NCAND];

    float gx1 = gt_boxes[g*6+0], gy1 = gt_boxes[g*6+1];
    float gx2 = gt_boxes[g*6+2], gy2 = gt_boxes[g*6+3];
    float gz1 = gt_boxes[g*6+4], gz2 = gt_boxes[g*6+5];
    float gx = (gx1+gx2)*0.5f, gy = (gy1+gy2)*0.5f, gz = (gz1+gz2)*0.5f;
    float sg = gx*gx + gy*gy + gz*gz;

    unsigned long long e[9];
    #pragma unroll
    for (int k = 0; k < 9; k++) e[k] = ~0ULL;

    if (wl == 3) {
        // direct: exactly 512 anchors = 8 per lane, all in registers
        #pragma unroll
        for (int j = 0; j < 8; j++) {
            int i = LVL3_START + lane + 64*j;
            if (i < n) {
                const float2* r = (const float2*)(anchors + (size_t)i*6);
                float2 p0 = r[0], p1 = r[1], p2 = r[2];
                float cx = (p0.x + p1.x) * 0.5f;
                float cy = (p0.y + p1.y) * 0.5f;
                float cz = (p2.x + p2.y) * 0.5f;
                float sa2 = cx*cx + cy*cy + cz*cz;
                float dot = cx*gx + cy*gy + cz*gz;
                float d2  = sa2 + sg - 2.0f*dot;
                e[j] = ((unsigned long long)f2ord(d2) << 32) | (unsigned)i;
            }
        }
    } else if (wl == 2) {
        // direct scan of level 2 (4096 anchors, L2-resident), static chain
        for (int i = LVL2_START + lane; i < LVL3_START; i += 64) {
            const float2* r = (const float2*)(anchors + (size_t)i*6);
            float2 p0 = r[0], p1 = r[1], p2 = r[2];
            float cx = (p0.x + p1.x) * 0.5f;
            float cy = (p0.y + p1.y) * 0.5f;
            float cz = (p2.x + p2.y) * 0.5f;
            float sa2 = cx*cx + cy*cy + cz*cz;
            float dot = cx*gx + cy*gy + cz*gz;
            float d2  = sa2 + sg - 2.0f*dot;
            unsigned long long x = ((unsigned long long)f2ord(d2) << 32) | (unsigned)i;
            if (x < e[8]) {
                #pragma unroll
                for (int k = 0; k < 9; k++) {     // static-index min/max chain
                    unsigned long long lo = (x < e[k]) ? x : e[k];
                    unsigned long long hi = (x < e[k]) ? e[k] : x;
                    e[k] = lo; x = hi;
                }
            }
        }
    } else {
        // segmented gather: lvl0 = 8 segments/lane, lvl1 = 1 segment/lane
        int segN = (wl == 0) ? SEG0 : SEG1;
        int J    = (wl == 0) ? 8 : 1;
        const unsigned* cc = (wl == 0) ? c0 : c1;
        const unsigned long long* ll = (wl == 0) ? l0 : l1;

        unsigned cs[8];
        unsigned tot = 0, ovf = 0;
        #pragma unroll
        for (int j = 0; j < 8; j++) {
            cs[j] = 0;
            if (j < J) {
                unsigned c = cc[(size_t)g * segN + lane + 64*j];
                cs[j] = c;
                if (c & OVF) ovf = 1; else tot += c;
            }
        }
        #pragma unroll
        for (int o = 32; o >= 1; o >>= 1) {
            tot += __shfl_xor(tot, o);
            ovf |= __shfl_xor(ovf, o);
        }

        if (!ovf && tot >= 9) {
            #pragma unroll
            for (int j = 0; j < 8; j++) {
                if (j < J) {
                    size_t segoff = ((size_t)g * segN + lane + 64*j) * QCAP;
                    unsigned c = cs[j];
                    for (unsigned s = 0; s < c; s++) {
                        unsigned long long x = ll[segoff + s];
                        if (x < e[8]) {
                            #pragma unroll
                            for (int k = 0; k < 9; k++) {
                                unsigned long long lo = (x < e[k]) ? x : e[k];
                                unsigned long long hi = (x < e[k]) ? e[k] : x;
                                e[k] = lo; x = hi;
                            }
                        }
                    }
                }
            }
        } else {
            // fallback: full exact rescan of level 0/1 (never expected)
            int s0 = c_lvl_start[wl], s1 = c_lvl_end[wl];
            for (int i = s0 + lane; i < s1; i += 64) {
                const float2* r = (const float2*)(anchors + (size_t)i*6);
                float2 p0 = r[0], p1 = r[1], p2 = r[2];
                float cx = (p0.x + p1.x) * 0.5f;
                float cy = (p0.y + p1.y) * 0.5f;
                float cz = (p2.x + p2.y) * 0.5f;
                float sa2 = cx*cx + cy*cy + cz*cz;
                float dot = cx*gx + cy*gy + cz*gz;
                float d2  = sa2 + sg - 2.0f*dot;
                unsigned long long x = ((unsigned long long)f2ord(d2) << 32) | (unsigned)i;
                if (x < e[8]) {
                    #pragma unroll
                    for (int k = 0; k < 9; k++) {
                        unsigned long long lo = (x < e[k]) ? x : e[k];
                        unsigned long long hi = (x < e[k]) ? e[k] : x;
                        e[k] = lo; x = hi;
                    }
                }
            }
        }
    }

    // exact top-9: 9 rounds of wave-wide argmin with removal.
    // packed keys are unique (anchor idx in low bits) -> one removal/round.
    #pragma unroll
    for (int r9 = 0; r9 < 9; r9++) {
        unsigned long long mn = e[0];
        #pragma unroll
        for (int j = 1; j < 9; j++) mn = (e[j] < mn) ? e[j] : mn;
        #pragma unroll
        for (int off = 32; off >= 1; off >>= 1) {
            unsigned long long o = __shfl_xor(mn, off);
            mn = (o < mn) ? o : mn;
        }
        if (lane == 0) scand[wl*9 + r9] = (int)(unsigned)mn;
        #pragma unroll
        for (int j = 0; j < 9; j++) e[j] = (e[j] == mn) ? ~0ULL : e[j];
    }
    __syncthreads();

    if (tid < 64) {
        float vg = (gx2 - gx1) * (gy2 - gy1) * (gz2 - gz1);
        bool valid = (tid < NCAND);
        float iou = 0.0f;
        int aidx = 0;
        float acx = 0.0f, acy = 0.0f, acz = 0.0f;
        if (valid) {
            aidx = scand[tid];
            float ax1 = anchors[aidx*6+0], ay1 = anchors[aidx*6+1];
            float ax2 = anchors[aidx*6+2], ay2 = anchors[aidx*6+3];
            float az1 = anchors[aidx*6+4], az2 = anchors[aidx*6+5];
            float va = (ax2 - ax1) * (ay2 - ay1) * (az2 - az1);
            float wx = fmaxf(fminf(ax2, gx2) - fmaxf(ax1, gx1), 0.0f);
            float wy = fmaxf(fminf(ay2, gy2) - fmaxf(ay1, gy1), 0.0f);
            float wz = fmaxf(fminf(az2, gz2) - fmaxf(az1, gz1), 0.0f);
            float inter = wx * wy * wz;
            iou = inter / (va + vg - inter + 1e-6f);
            acx = (ax1 + ax2) * 0.5f;
            acy = (ay1 + ay2) * 0.5f;
            acz = (az1 + az2) * 0.5f;
        }

        float s = iou;
        #pragma unroll
        for (int o = 32; o >= 1; o >>= 1) s += __shfl_xor(s, o);
        float mean = s / 36.0f;
        float dev = valid ? (iou - mean) : 0.0f;
        float s2 = dev * dev;
        #pragma unroll
        for (int o = 32; o >= 1; o >>= 1) s2 += __shfl_xor(s2, o);
        float thr = fmaxf(mean + sqrtf(s2 / 35.0f), 0.0f);  // MIN_IOU = 0

        if (valid && iou >= thr) {
            bool inside = (acx >= gx1) & (acx <= gx2) &
                          (acy >= gy1) & (acy <= gy2) &
                          (acz >= gz1) & (acz <= gz2);
            if (inside) {
                unsigned long long p =
                    ((unsigned long long)__float_as_uint(iou) << 32) | (unsigned)(~(unsigned)g);
                atomicMax(&packed[aidx], p);
            }
        }
    }
}

__global__ void phaseD(const unsigned long long* __restrict__ packed,
                       float* __restrict__ out, int n) {
    int i = blockIdx.x * blockDim.x + threadIdx.x;
    if (i >= n) return;
    unsigned long long p = packed[i];
    float gt_f, iou_f, lab_f;
    if (p == 0ULL) {
        gt_f = -1.0f; iou_f = 0.0f; lab_f = 0.0f;
    } else {
        unsigned low = (unsigned)p;
        int gidx = (int)(~low);
        iou_f = __uint_as_float((unsigned)(p >> 32));
        gt_f = (float)gidx;
        lab_f = 1.0f;
    }
    out[i]       = gt_f;
    out[n + i]   = iou_f;
    out[2*n + i] = lab_f;
}

extern "C" void kernel_launch(void* const* d_in, const int* in_sizes, int n_in,
                              void* d_out, int out_size, void* d_ws, size_t ws_size,
                              hipStream_t stream) {
    const float* gt      = (const float*)d_in[0];
    const float* anchors = (const float*)d_in[1];
    int m = in_sizes[0] / 6;   // 64
    int n = in_sizes[1] / 6;   // 299520

    char* ws = (char*)d_ws;
    unsigned long long* packed = (unsigned long long*)ws;                    // n*8
    size_t off = (size_t)n * 8;
    unsigned long long* l0 = (unsigned long long*)(ws + off);                // 64*512*64*8 = 16 MiB
    off += (size_t)64 * SEG0 * QCAP * 8;
    unsigned long long* l1 = (unsigned long long*)(ws + off);                // 64*64*64*8 = 2 MiB
    off += (size_t)64 * SEG1 * QCAP * 8;
    unsigned* c0 = (unsigned*)(ws + off);                                    // 64*512*4
    off += (size_t)64 * SEG0 * 4;
    unsigned* c1 = (unsigned*)(ws + off);                                    // 64*64*4
    float* out = (float*)d_out;

    scanK<<<SEG0 + SEG1, 256, 0, stream>>>(anchors, gt, l0, l1, c0, c1, packed, n, m);
    selectC<<<m, 256, 0, stream>>>(l0, l1, c0, c1, anchors, gt, packed, n);
    phaseD<<<(n + 255) / 256, 256, 0, stream>>>(packed, out, n);
}

// Round 7
// 46.620 us; speedup vs baseline: 5.9825x; 1.1886x over previous
//
#include <hip/hip_runtime.h>
#include <cstdint>

// ATSS matcher, segmented filter-then-select (exact, 3 kernels):
//  scanK (576 blocks x 512 anchors, levels 0/1 only; bounds 512-aligned):
//    zeroes packed[] for its range (blocks 0-8 also zero the lvl-2/3 tail),
//    centers in registers, d2<=T gate -> per-GT LDS-atomic index -> DIRECT
//    store into the block's private segment lists[gt][seg][QCAP]. Counts
//    written unconditionally, non-atomically -> no zero-init, poison-proof.
//    Overflow sets a flag bit -> selectC exact fallback, so correctness does
//    NOT depend on T or QCAP.
//  selectC (64 blocks, 4 waves): register-resident exact top-9 per level
//    (9 rounds of wave argmin-with-removal on packed u64 == exact d2 order +
//    lowest-index tie-break, matching jax top_k).
//      wave0: lvl0 segment gather (8 segs/lane, first-entry prefetch)
//      wave1: lvl1 segment gather (1 seg/lane)
//      wave2: direct scan lvl2 first half (4-wide batched loads)
//      wave3: direct scan lvl3 (4-wide) then lvl2 second half (4-wide)
//    lvl2 halves' top-9s (full u64) merge via an 18-candidate wave argmin
//    (exact: top9(U) = top9(top9(A) u top9(B)); unique keys). Fallback full
//    rescan if a gather undercollects (<9) or overflowed (never expected).
//    Then wave 0: fused IoU -> mean+std(ddof=1) threshold -> center-inside ->
//    atomicMax (iou<<32 | ~gt) argmax scatter.
//  phaseD: decode packed -> (matched_gt, matched_iou, labels) f32.
//
// R5 lesson: cooperative grid.sync() costs ~100+ us on MI355X (cross-XCD L2
// coherence) — kernel boundaries are far cheaper. R6 lesson: a single-wave
// 64-iteration load+insert loop serializes at ~full memory latency per
// iteration (~40 us); batch loads 4-wide and split across waves.
// All arithmetic forms (center=(lo+hi)*0.5f, d2=sa+sg-2*dot, IoU, threshold)
// are byte-identical to the verified R3/R6 kernels so selection matches.

#define NCAND 36
#define QCAP 64           // per-(block,gt) segment capacity; E[fill] <= 3.8
#define OVF  0x80000000u
#define LVL1_START 262144
#define LVL2_START 294912
#define LVL2_MID   296960
#define LVL3_START 299008
#define SEG0 512          // level-0 segments (blocks 0..511)
#define SEG1 64           // level-1 segments (blocks 512..575)

__device__ __constant__ int   c_lvl_start[2] = {0, 262144};
__device__ __constant__ int   c_lvl_end[2]   = {262144, 294912};
// (3 * r9_bulk)^2 per level; r9_bulk = (9 / (4/3 pi rho))^(1/3), rho = lvl/512^3
__device__ __constant__ float c_T[2] = {961.0f, 3844.0f};

// order-preserving float->uint (handles negative d2 from cancellation)
__device__ __forceinline__ unsigned f2ord(float f) {
    unsigned u = __float_as_uint(f);
    return (u & 0x80000000u) ? ~u : (u | 0x80000000u);
}

// branch-guarded static-index sorted-insert into ascending e[9] (registers)
__device__ __forceinline__ void insertChain(unsigned long long e[9], unsigned long long x) {
    if (x < e[8]) {
        #pragma unroll
        for (int k = 0; k < 9; k++) {
            unsigned long long lo = (x < e[k]) ? x : e[k];
            unsigned long long hi = (x < e[k]) ? e[k] : x;
            e[k] = lo; x = hi;
        }
    }
}

// exact wave-wide top-9: 9 rounds of argmin-with-removal (unique keys).
// lane 0 writes the 9 winners (full u64, ascending) to out9.
__device__ __forceinline__ void waveTop9(unsigned long long e[9], int lane,
                                         unsigned long long* out9) {
    #pragma unroll
    for (int r9 = 0; r9 < 9; r9++) {
        unsigned long long mn = e[0];
        #pragma unroll
        for (int j = 1; j < 9; j++) mn = (e[j] < mn) ? e[j] : mn;
        #pragma unroll
        for (int off = 32; off >= 1; off >>= 1) {
            unsigned long long o = __shfl_xor(mn, off);
            mn = (o < mn) ? o : mn;
        }
        if (lane == 0) out9[r9] = mn;
        #pragma unroll
        for (int j = 0; j < 9; j++) e[j] = (e[j] == mn) ? ~0ULL : e[j];
    }
}

// direct scan of anchor range [s0,s1): 4-wide batched loads (12 independent
// loads in flight), exact same center/d2 arithmetic as everywhere else.
__device__ __forceinline__ void scanRange(const float* __restrict__ anchors,
                                          int s0, int s1, int lane,
                                          float gx, float gy, float gz, float sg,
                                          unsigned long long e[9]) {
    int i = s0 + lane;
    for (; i + 192 < s1; i += 256) {
        float2 q[4][3];
        #pragma unroll
        for (int u = 0; u < 4; u++) {
            const float2* r = (const float2*)(anchors + (size_t)(i + u*64)*6);
            q[u][0] = r[0]; q[u][1] = r[1]; q[u][2] = r[2];
        }
        #pragma unroll
        for (int u = 0; u < 4; u++) {
            float cx = (q[u][0].x + q[u][1].x) * 0.5f;
            float cy = (q[u][0].y + q[u][1].y) * 0.5f;
            float cz = (q[u][2].x + q[u][2].y) * 0.5f;
            float sa2 = cx*cx + cy*cy + cz*cz;
            float dot = cx*gx + cy*gy + cz*gz;
            float d2  = sa2 + sg - 2.0f*dot;
            insertChain(e, ((unsigned long long)f2ord(d2) << 32) | (unsigned)(i + u*64));
        }
    }
    for (; i < s1; i += 64) {
        const float2* r = (const float2*)(anchors + (size_t)i*6);
        float2 p0 = r[0], p1 = r[1], p2 = r[2];
        float cx = (p0.x + p1.x) * 0.5f;
        float cy = (p0.y + p1.y) * 0.5f;
        float cz = (p2.x + p2.y) * 0.5f;
        float sa2 = cx*cx + cy*cy + cz*cz;
        float dot = cx*gx + cy*gy + cz*gz;
        float d2  = sa2 + sg - 2.0f*dot;
        insertChain(e, ((unsigned long long)f2ord(d2) << 32) | (unsigned)i);
    }
}

// one block per 512-anchor range, levels 0/1. 2 anchors/thread in regs,
// all m GTs from LDS. Direct segmented stores; non-atomic count publish.
// (byte-identical to the verified R6 scanK)
__global__ void scanK(const float* __restrict__ anchors, const float* __restrict__ gt_boxes,
                      unsigned long long* __restrict__ l0, unsigned long long* __restrict__ l1,
                      unsigned* __restrict__ c0, unsigned* __restrict__ c1,
                      unsigned long long* __restrict__ packed, int n, int m) {
    int b    = blockIdx.x;
    int tid  = threadIdx.x;
    int base = b << 9;
    int lvl  = (base >= LVL1_START) ? 1 : 0;
    float T  = c_T[lvl];

    int segN = (lvl == 0) ? SEG0 : SEG1;
    int seg  = (lvl == 0) ? b : (b - SEG0);
    unsigned long long* lseg = (lvl == 0) ? l0 : l1;

    __shared__ float4 gt4[64];
    __shared__ unsigned qcnt[64];

    if (tid < 64) {
        qcnt[tid] = 0;
        if (tid < m) {
            int g = tid;
            float gx = (gt_boxes[g*6+0] + gt_boxes[g*6+2]) * 0.5f;
            float gy = (gt_boxes[g*6+1] + gt_boxes[g*6+3]) * 0.5f;
            float gz = (gt_boxes[g*6+4] + gt_boxes[g*6+5]) * 0.5f;
            float sg = gx*gx + gy*gy + gz*gz;
            gt4[g] = make_float4(gx, gy, gz, sg);
        }
    }
    if (b < 9) {   // zero packed[] for the level-2/3 tail (4608 entries)
        int s = LVL2_START + (b << 9) + tid;
        if (s < n) packed[s] = 0ULL;
        if (s + 256 < n) packed[s + 256] = 0ULL;
    }
    __syncthreads();

    float ax[2], ay[2], az[2], sa[2];
    int   ai[2];
    #pragma unroll
    for (int k = 0; k < 2; k++) {
        int a = base + tid + k*256;
        ai[k] = a;
        const float2* r = (const float2*)(anchors + (size_t)a*6);
        float2 p0 = r[0], p1 = r[1], p2 = r[2];  // (x1,y1)(x2,y2)(z1,z2)
        float cx = (p0.x + p1.x) * 0.5f;
        float cy = (p0.y + p1.y) * 0.5f;
        float cz = (p2.x + p2.y) * 0.5f;
        ax[k] = cx; ay[k] = cy; az[k] = cz;
        sa[k] = cx*cx + cy*cy + cz*cz;
        packed[a] = 0ULL;
    }

    for (int g = 0; g < m; g++) {
        float4 gv = gt4[g];
        size_t segoff = ((size_t)g * segN + seg) * QCAP;
        #pragma unroll
        for (int k = 0; k < 2; k++) {
            float dot = ax[k]*gv.x + ay[k]*gv.y + az[k]*gv.z;
            float d2  = sa[k] + gv.w - 2.0f*dot;   // same algebraic form as reference
            if (d2 <= T) {
                unsigned idx = atomicAdd(&qcnt[g], 1u);   // LDS atomic (R3-verified)
                if (idx < QCAP) {
                    unsigned long long p =
                        ((unsigned long long)f2ord(d2) << 32) | (unsigned)ai[k];
                    lseg[segoff + idx] = p;   // fire-and-forget 8B store
                }
            }
        }
    }
    __syncthreads();

    // publish counts: unconditional, non-atomic (no zero-init needed anywhere)
    if (tid < 64) {
        unsigned c = qcnt[tid];
        unsigned cw = (c > QCAP) ? OVF : c;
        if (lvl == 0) c0[tid * SEG0 + seg] = cw;
        else          c1[tid * SEG1 + seg] = cw;
    }
}

// one block (256 threads = 4 waves) per GT. All candidate state in named
// registers (static indexing only).
__global__ void selectC(const unsigned long long* __restrict__ l0,
                        const unsigned long long* __restrict__ l1,
                        const unsigned* __restrict__ c0,
                        const unsigned* __restrict__ c1,
                        const float* __restrict__ anchors,
                        const float* __restrict__ gt_boxes,
                        unsigned long long* __restrict__ packed, int n) {
    int g = blockIdx.x;
    int tid = threadIdx.x;     // 0..255
    int wl  = tid >> 6;        // wave id
    int lane = tid & 63;
    __shared__ unsigned long long cands[NCAND];  // per-level top-9, ascending
    __shared__ unsigned long long cand2[18];     // lvl2 half-results

    float gx1 = gt_boxes[g*6+0], gy1 = gt_boxes[g*6+1];
    float gx2 = gt_boxes[g*6+2], gy2 = gt_boxes[g*6+3];
    float gz1 = gt_boxes[g*6+4], gz2 = gt_boxes[g*6+5];
    float gx = (gx1+gx2)*0.5f, gy = (gy1+gy2)*0.5f, gz = (gz1+gz2)*0.5f;
    float sg = gx*gx + gy*gy + gz*gz;

    unsigned long long e[9];
    #pragma unroll
    for (int k = 0; k < 9; k++) e[k] = ~0ULL;

    if (wl == 3) {
        // lvl3 direct: 512 anchors, 2 batches
        scanRange(anchors, LVL3_START, n, lane, gx, gy, gz, sg, e);
        waveTop9(e, lane, &cands[27]);
        #pragma unroll
        for (int k = 0; k < 9; k++) e[k] = ~0ULL;
        // lvl2 second half: 2048 anchors, 8 batches
        scanRange(anchors, LVL2_MID, LVL3_START, lane, gx, gy, gz, sg, e);
        waveTop9(e, lane, &cand2[9]);
    } else if (wl == 2) {
        // lvl2 first half: 2048 anchors, 8 batches
        scanRange(anchors, LVL2_START, LVL2_MID, lane, gx, gy, gz, sg, e);
        waveTop9(e, lane, &cand2[0]);
    } else {
        // segmented gather: lvl0 = 8 segments/lane, lvl1 = 1 segment/lane
        int segN = (wl == 0) ? SEG0 : SEG1;
        int J    = (wl == 0) ? 8 : 1;
        const unsigned* cc = (wl == 0) ? c0 : c1;
        const unsigned long long* ll = (wl == 0) ? l0 : l1;
        size_t sb = (size_t)g * segN * QCAP;

        unsigned cs[8];
        unsigned long long q0[8];
        unsigned tot = 0, ovf = 0;
        #pragma unroll
        for (int j = 0; j < 8; j++) {
            cs[j] = 0; q0[j] = ~0ULL;
            if (j < J) {
                // counts + first-entry prefetch: all independent, in flight together
                cs[j] = cc[(size_t)g * segN + lane + 64*j];
                q0[j] = ll[sb + (size_t)(lane + 64*j) * QCAP];
            }
        }
        #pragma unroll
        for (int j = 0; j < 8; j++) {
            if (j < J) { if (cs[j] & OVF) ovf = 1; else tot += cs[j]; }
        }
        #pragma unroll
        for (int o = 32; o >= 1; o >>= 1) {
            tot += __shfl_xor(tot, o);
            ovf |= __shfl_xor(ovf, o);
        }

        if (!ovf && tot >= 9) {
            #pragma unroll
            for (int j = 0; j < 8; j++) {
                if (j < J) {
                    unsigned c = cs[j];
                    if (c >= 1) insertChain(e, q0[j]);
                    size_t segoff = sb + (size_t)(lane + 64*j) * QCAP;
                    for (unsigned s = 1; s < c; s++)      // rare (E[c] <= 3.8)
                        insertChain(e, ll[segoff + s]);
                }
            }
        } else {
            // fallback: full exact rescan of level 0/1 (never expected)
            scanRange(anchors, c_lvl_start[wl], c_lvl_end[wl], lane, gx, gy, gz, sg, e);
        }
        waveTop9(e, lane, &cands[wl*9]);
    }
    __syncthreads();

    // merge the two lvl2 half top-9s (18 candidates, 1 per lane) exactly
    if (wl == 2) {
        unsigned long long v = (lane < 18) ? cand2[lane] : ~0ULL;
        #pragma unroll
        for (int r9 = 0; r9 < 9; r9++) {
            unsigned long long mn = v;
            #pragma unroll
            for (int off = 32; off >= 1; off >>= 1) {
                unsigned long long o = __shfl_xor(mn, off);
                mn = (o < mn) ? o : mn;
            }
            if (lane == 0) cands[18 + r9] = mn;
            v = (v == mn) ? ~0ULL : v;
        }
    }
    __syncthreads();

    if (tid < 64) {
        float vg = (gx2 - gx1) * (gy2 - gy1) * (gz2 - gz1);
        bool valid = (tid < NCAND);
        float iou = 0.0f;
        int aidx = 0;
        float acx = 0.0f, acy = 0.0f, acz = 0.0f;
        if (valid) {
            aidx = (int)(unsigned)cands[tid];
            float ax1 = anchors[aidx*6+0], ay1 = anchors[aidx*6+1];
            float ax2 = anchors[aidx*6+2], ay2 = anchors[aidx*6+3];
            float az1 = anchors[aidx*6+4], az2 = anchors[aidx*6+5];
            float va = (ax2 - ax1) * (ay2 - ay1) * (az2 - az1);
            float wx = fmaxf(fminf(ax2, gx2) - fmaxf(ax1, gx1), 0.0f);
            float wy = fmaxf(fminf(ay2, gy2) - fmaxf(ay1, gy1), 0.0f);
            float wz = fmaxf(fminf(az2, gz2) - fmaxf(az1, gz1), 0.0f);
            float inter = wx * wy * wz;
            iou = inter / (va + vg - inter + 1e-6f);
            acx = (ax1 + ax2) * 0.5f;
            acy = (ay1 + ay2) * 0.5f;
            acz = (az1 + az2) * 0.5f;
        }

        float s = iou;
        #pragma unroll
        for (int o = 32; o >= 1; o >>= 1) s += __shfl_xor(s, o);
        float mean = s / 36.0f;
        float dev = valid ? (iou - mean) : 0.0f;
        float s2 = dev * dev;
        #pragma unroll
        for (int o = 32; o >= 1; o >>= 1) s2 += __shfl_xor(s2, o);
        float thr = fmaxf(mean + sqrtf(s2 / 35.0f), 0.0f);  // MIN_IOU = 0

        if (valid && iou >= thr) {
            bool inside = (acx >= gx1) & (acx <= gx2) &
                          (acy >= gy1) & (acy <= gy2) &
                          (acz >= gz1) & (acz <= gz2);
            if (inside) {
                unsigned long long p =
                    ((unsigned long long)__float_as_uint(iou) << 32) | (unsigned)(~(unsigned)g);
                atomicMax(&packed[aidx], p);
            }
        }
    }
}

__global__ void phaseD(const unsigned long long* __restrict__ packed,
                       float* __restrict__ out, int n) {
    int i = blockIdx.x * blockDim.x + threadIdx.x;
    if (i >= n) return;
    unsigned long long p = packed[i];
    float gt_f, iou_f, lab_f;
    if (p == 0ULL) {
        gt_f = -1.0f; iou_f = 0.0f; lab_f = 0.0f;
    } else {
        unsigned low = (unsigned)p;
        int gidx = (int)(~low);
        iou_f = __uint_as_float((unsigned)(p >> 32));
        gt_f = (float)gidx;
        lab_f = 1.0f;
    }
    out[i]       = gt_f;
    out[n + i]   = iou_f;
    out[2*n + i] = lab_f;
}

extern "C" void kernel_launch(void* const* d_in, const int* in_sizes, int n_in,
                              void* d_out, int out_size, void* d_ws, size_t ws_size,
                              hipStream_t stream) {
    const float* gt      = (const float*)d_in[0];
    const float* anchors = (const float*)d_in[1];
    int m = in_sizes[0] / 6;   // 64
    int n = in_sizes[1] / 6;   // 299520

    char* ws = (char*)d_ws;
    unsigned long long* packed = (unsigned long long*)ws;                    // n*8
    size_t off = (size_t)n * 8;
    unsigned long long* l0 = (unsigned long long*)(ws + off);                // 64*512*64*8 = 16 MiB
    off += (size_t)64 * SEG0 * QCAP * 8;
    unsigned long long* l1 = (unsigned long long*)(ws + off);                // 64*64*64*8 = 2 MiB
    off += (size_t)64 * SEG1 * QCAP * 8;
    unsigned* c0 = (unsigned*)(ws + off);                                    // 64*512*4
    off += (size_t)64 * SEG0 * 4;
    unsigned* c1 = (unsigned*)(ws + off);                                    // 64*64*4
    float* out = (float*)d_out;

    scanK<<<SEG0 + SEG1, 256, 0, stream>>>(anchors, gt, l0, l1, c0, c1, packed, n, m);
    selectC<<<m, 256, 0, stream>>>(l0, l1, c0, c1, anchors, gt, packed, n);
    phaseD<<<(n + 255) / 256, 256, 0, stream>>>(packed, out, n);
}

// Round 8
// 45.764 us; speedup vs baseline: 6.0944x; 1.0187x over previous
//
#include <hip/hip_runtime.h>
#include <cstdint>

// ATSS matcher, segmented filter-then-select (exact, 3 kernels):
//  scanK (585 blocks):
//    blocks 0..575: one 512-anchor range each, levels 0/1. Zero packed[] for
//      own range (blocks 0-8 also the lvl-2/3 tail), centers in registers,
//      d2<=T gate -> per-GT LDS-atomic index -> direct store into the block's
//      private segment lists[gt][seg][QCAP]. Counts published unconditionally,
//      non-atomically -> no zero-init, poison-proof. Overflow sets a flag ->
//      selectC exact fallback, so correctness does NOT depend on T or QCAP.
//    blocks 576..584: build c4 (float4 cx,cy,cz,|c|^2) for the 4608 lvl-2/3
//      anchors (same arithmetic ops as everywhere -> bit-identical keys).
//  selectC (64 blocks, 4 waves): register-resident exact top-9 per level
//    (9 rounds of wave argmin-with-removal on packed u64 == exact d2 order +
//    lowest-index tie-break, matching jax top_k).
//      wave0: lvl0 gather, 8 segs/lane, entries[0..3] prefetched per segment
//             (independent ulonglong2 loads; serial tail only for c>4, rare)
//      wave1: lvl1 gather, 1 seg/lane, entries[0..7] prefetched (tail c>8)
//      wave2: direct scan lvl2 first half on c4 (8-wide float4 batches)
//      wave3: direct scan lvl3 then lvl2 second half on c4 (8-wide)
//    lvl2 halves merge via an 18-candidate wave argmin (exact; unique keys).
//    Fallback full rescan if a gather undercollects (<9) or overflowed.
//    Then wave 0: fused IoU -> mean+std(ddof=1) threshold -> center-inside ->
//    atomicMax (iou<<32 | ~gt) argmax scatter.
//  phaseD: decode packed -> (matched_gt, matched_iou, labels) f32.
//
// R5 lesson: cooperative grid.sync() costs ~100+ us on MI355X (cross-XCD L2
// coherence) — kernel boundaries are far cheaper. R6/R7 lesson: single-wave
// loops whose loads are serialized by data/control dependence pay full cold
// latency (~800-900 cy) per iteration; fix by prefetching contiguous entries
// unconditionally and shrinking per-anchor loads to one float4.
// All arithmetic forms (center=(lo+hi)*0.5f, d2=sa+sg-2*dot, IoU, threshold)
// are byte-identical to the verified R3/R6/R7 kernels so selection matches.

#define NCAND 36
#define QCAP 64           // per-(block,gt) segment capacity; E[fill] <= 3.8
#define OVF  0x80000000u
#define LVL1_START 262144
#define LVL2_START 294912
#define LVL3_START 299008
#define SEG0 512          // level-0 segments (blocks 0..511)
#define SEG1 64           // level-1 segments (blocks 512..575)
#define C4BLOCKS 9        // builder blocks for c4 (4608 anchors)

__device__ __constant__ int   c_lvl_start[2] = {0, 262144};
__device__ __constant__ int   c_lvl_end[2]   = {262144, 294912};
// (3 * r9_bulk)^2 per level; r9_bulk = (9 / (4/3 pi rho))^(1/3), rho = lvl/512^3
__device__ __constant__ float c_T[2] = {961.0f, 3844.0f};

// order-preserving float->uint (handles negative d2 from cancellation)
__device__ __forceinline__ unsigned f2ord(float f) {
    unsigned u = __float_as_uint(f);
    return (u & 0x80000000u) ? ~u : (u | 0x80000000u);
}

// branch-guarded static-index sorted-insert into ascending e[9] (registers)
__device__ __forceinline__ void insertChain(unsigned long long e[9], unsigned long long x) {
    if (x < e[8]) {
        #pragma unroll
        for (int k = 0; k < 9; k++) {
            unsigned long long lo = (x < e[k]) ? x : e[k];
            unsigned long long hi = (x < e[k]) ? e[k] : x;
            e[k] = lo; x = hi;
        }
    }
}

// exact wave-wide top-9: 9 rounds of argmin-with-removal (unique keys).
// lane 0 writes the 9 winners (full u64, ascending) to out9.
__device__ __forceinline__ void waveTop9(unsigned long long e[9], int lane,
                                         unsigned long long* out9) {
    #pragma unroll
    for (int r9 = 0; r9 < 9; r9++) {
        unsigned long long mn = e[0];
        #pragma unroll
        for (int j = 1; j < 9; j++) mn = (e[j] < mn) ? e[j] : mn;
        #pragma unroll
        for (int off = 32; off >= 1; off >>= 1) {
            unsigned long long o = __shfl_xor(mn, off);
            mn = (o < mn) ? o : mn;
        }
        if (lane == 0) out9[r9] = mn;
        #pragma unroll
        for (int j = 0; j < 9; j++) e[j] = (e[j] == mn) ? ~0ULL : e[j];
    }
}

// direct scan over precomputed c4 (rel indices into [LVL2_START, n)):
// one float4 load per anchor, 8-wide batches (all ranges are 512-multiples).
__device__ __forceinline__ void scanC4(const float4* __restrict__ c4,
                                       int rel0, int rel1, int lane,
                                       float gx, float gy, float gz, float sg,
                                       unsigned long long e[9]) {
    int i = rel0 + lane;
    for (; i + 448 < rel1; i += 512) {
        float4 q[8];
        #pragma unroll
        for (int u = 0; u < 8; u++) q[u] = c4[i + u*64];
        #pragma unroll
        for (int u = 0; u < 8; u++) {
            float dot = q[u].x*gx + q[u].y*gy + q[u].z*gz;
            float d2  = q[u].w + sg - 2.0f*dot;
            insertChain(e, ((unsigned long long)f2ord(d2) << 32)
                           | (unsigned)(LVL2_START + i + u*64));
        }
    }
    for (; i < rel1; i += 64) {
        float4 q = c4[i];
        float dot = q.x*gx + q.y*gy + q.z*gz;
        float d2  = q.w + sg - 2.0f*dot;
        insertChain(e, ((unsigned long long)f2ord(d2) << 32)
                       | (unsigned)(LVL2_START + i));
    }
}

// raw-anchor scan (fallback path only, never expected)
__device__ __forceinline__ void scanRange(const float* __restrict__ anchors,
                                          int s0, int s1, int lane,
                                          float gx, float gy, float gz, float sg,
                                          unsigned long long e[9]) {
    int i = s0 + lane;
    for (; i + 192 < s1; i += 256) {
        float2 q[4][3];
        #pragma unroll
        for (int u = 0; u < 4; u++) {
            const float2* r = (const float2*)(anchors + (size_t)(i + u*64)*6);
            q[u][0] = r[0]; q[u][1] = r[1]; q[u][2] = r[2];
        }
        #pragma unroll
        for (int u = 0; u < 4; u++) {
            float cx = (q[u][0].x + q[u][1].x) * 0.5f;
            float cy = (q[u][0].y + q[u][1].y) * 0.5f;
            float cz = (q[u][2].x + q[u][2].y) * 0.5f;
            float sa2 = cx*cx + cy*cy + cz*cz;
            float dot = cx*gx + cy*gy + cz*gz;
            float d2  = sa2 + sg - 2.0f*dot;
            insertChain(e, ((unsigned long long)f2ord(d2) << 32) | (unsigned)(i + u*64));
        }
    }
    for (; i < s1; i += 64) {
        const float2* r = (const float2*)(anchors + (size_t)i*6);
        float2 p0 = r[0], p1 = r[1], p2 = r[2];
        float cx = (p0.x + p1.x) * 0.5f;
        float cy = (p0.y + p1.y) * 0.5f;
        float cz = (p2.x + p2.y) * 0.5f;
        float sa2 = cx*cx + cy*cy + cz*cz;
        float dot = cx*gx + cy*gy + cz*gz;
        float d2  = sa2 + sg - 2.0f*dot;
        insertChain(e, ((unsigned long long)f2ord(d2) << 32) | (unsigned)i);
    }
}

// blocks 0..575: one 512-anchor range, levels 0/1 (R6-verified scan).
// blocks 576..584: c4 builder for levels 2/3.
__global__ void scanK(const float* __restrict__ anchors, const float* __restrict__ gt_boxes,
                      unsigned long long* __restrict__ l0, unsigned long long* __restrict__ l1,
                      unsigned* __restrict__ c0, unsigned* __restrict__ c1,
                      unsigned long long* __restrict__ packed,
                      float4* __restrict__ c4, int n, int m) {
    int b    = blockIdx.x;
    int tid  = threadIdx.x;

    if (b >= SEG0 + SEG1) {   // c4 builder: 512 anchors per block, 2 per thread
        int bb = b - (SEG0 + SEG1);
        int i0 = LVL2_START + (bb << 9) + tid;
        #pragma unroll
        for (int k = 0; k < 2; k++) {
            int i = i0 + k*256;
            if (i < n) {
                const float2* r = (const float2*)(anchors + (size_t)i*6);
                float2 p0 = r[0], p1 = r[1], p2 = r[2];
                float cx = (p0.x + p1.x) * 0.5f;
                float cy = (p0.y + p1.y) * 0.5f;
                float cz = (p2.x + p2.y) * 0.5f;
                float sa2 = cx*cx + cy*cy + cz*cz;
                c4[i - LVL2_START] = make_float4(cx, cy, cz, sa2);
            }
        }
        return;
    }

    int base = b << 9;
    int lvl  = (base >= LVL1_START) ? 1 : 0;
    float T  = c_T[lvl];

    int segN = (lvl == 0) ? SEG0 : SEG1;
    int seg  = (lvl == 0) ? b : (b - SEG0);
    unsigned long long* lseg = (lvl == 0) ? l0 : l1;

    __shared__ float4 gt4[64];
    __shared__ unsigned qcnt[64];

    if (tid < 64) {
        qcnt[tid] = 0;
        if (tid < m) {
            int g = tid;
            float gx = (gt_boxes[g*6+0] + gt_boxes[g*6+2]) * 0.5f;
            float gy = (gt_boxes[g*6+1] + gt_boxes[g*6+3]) * 0.5f;
            float gz = (gt_boxes[g*6+4] + gt_boxes[g*6+5]) * 0.5f;
            float sg = gx*gx + gy*gy + gz*gz;
            gt4[g] = make_float4(gx, gy, gz, sg);
        }
    }
    if (b < 9) {   // zero packed[] for the level-2/3 tail (4608 entries)
        int s = LVL2_START + (b << 9) + tid;
        if (s < n) packed[s] = 0ULL;
        if (s + 256 < n) packed[s + 256] = 0ULL;
    }
    __syncthreads();

    float ax[2], ay[2], az[2], sa[2];
    int   ai[2];
    #pragma unroll
    for (int k = 0; k < 2; k++) {
        int a = base + tid + k*256;
        ai[k] = a;
        const float2* r = (const float2*)(anchors + (size_t)a*6);
        float2 p0 = r[0], p1 = r[1], p2 = r[2];  // (x1,y1)(x2,y2)(z1,z2)
        float cx = (p0.x + p1.x) * 0.5f;
        float cy = (p0.y + p1.y) * 0.5f;
        float cz = (p2.x + p2.y) * 0.5f;
        ax[k] = cx; ay[k] = cy; az[k] = cz;
        sa[k] = cx*cx + cy*cy + cz*cz;
        packed[a] = 0ULL;
    }

    for (int g = 0; g < m; g++) {
        float4 gv = gt4[g];
        size_t segoff = ((size_t)g * segN + seg) * QCAP;
        #pragma unroll
        for (int k = 0; k < 2; k++) {
            float dot = ax[k]*gv.x + ay[k]*gv.y + az[k]*gv.z;
            float d2  = sa[k] + gv.w - 2.0f*dot;   // same algebraic form as reference
            if (d2 <= T) {
                unsigned idx = atomicAdd(&qcnt[g], 1u);   // LDS atomic (R3-verified)
                if (idx < QCAP) {
                    unsigned long long p =
                        ((unsigned long long)f2ord(d2) << 32) | (unsigned)ai[k];
                    lseg[segoff + idx] = p;   // fire-and-forget 8B store
                }
            }
        }
    }
    __syncthreads();

    // publish counts: unconditional, non-atomic (no zero-init needed anywhere)
    if (tid < 64) {
        unsigned c = qcnt[tid];
        unsigned cw = (c > QCAP) ? OVF : c;
        if (lvl == 0) c0[tid * SEG0 + seg] = cw;
        else          c1[tid * SEG1 + seg] = cw;
    }
}

// one block (256 threads = 4 waves) per GT. All candidate state in named
// registers (static indexing only).
__global__ void selectC(const unsigned long long* __restrict__ l0,
                        const unsigned long long* __restrict__ l1,
                        const unsigned* __restrict__ c0,
                        const unsigned* __restrict__ c1,
                        const float* __restrict__ anchors,
                        const float* __restrict__ gt_boxes,
                        const float4* __restrict__ c4,
                        unsigned long long* __restrict__ packed, int n) {
    int g = blockIdx.x;
    int tid = threadIdx.x;     // 0..255
    int wl  = tid >> 6;        // wave id
    int lane = tid & 63;
    __shared__ unsigned long long cands[NCAND];  // per-level top-9, ascending
    __shared__ unsigned long long cand2[18];     // lvl2 half-results

    float gx1 = gt_boxes[g*6+0], gy1 = gt_boxes[g*6+1];
    float gx2 = gt_boxes[g*6+2], gy2 = gt_boxes[g*6+3];
    float gz1 = gt_boxes[g*6+4], gz2 = gt_boxes[g*6+5];
    float gx = (gx1+gx2)*0.5f, gy = (gy1+gy2)*0.5f, gz = (gz1+gz2)*0.5f;
    float sg = gx*gx + gy*gy + gz*gz;

    unsigned long long e[9];
    #pragma unroll
    for (int k = 0; k < 9; k++) e[k] = ~0ULL;

    if (wl == 3) {
        // lvl3 direct: 512 anchors = 1 batch of 8 float4/lane
        scanC4(c4, LVL3_START - LVL2_START, n - LVL2_START, lane, gx, gy, gz, sg, e);
        waveTop9(e, lane, &cands[27]);
        #pragma unroll
        for (int k = 0; k < 9; k++) e[k] = ~0ULL;
        // lvl2 second half: 2048 anchors = 4 batches
        scanC4(c4, 2048, LVL3_START - LVL2_START, lane, gx, gy, gz, sg, e);
        waveTop9(e, lane, &cand2[9]);
    } else if (wl == 2) {
        // lvl2 first half: 2048 anchors = 4 batches
        scanC4(c4, 0, 2048, lane, gx, gy, gz, sg, e);
        waveTop9(e, lane, &cand2[0]);
    } else if (wl == 1) {
        // lvl1 gather: 1 segment/lane, entries[0..7] prefetched unconditionally
        size_t sb = (size_t)g * SEG1 * QCAP;
        unsigned c = c1[(size_t)g * SEG1 + lane];
        size_t so = sb + (size_t)lane * QCAP;
        ulonglong2 q01 = *(const ulonglong2*)(l1 + so);
        ulonglong2 q23 = *(const ulonglong2*)(l1 + so + 2);
        ulonglong2 q45 = *(const ulonglong2*)(l1 + so + 4);
        ulonglong2 q67 = *(const ulonglong2*)(l1 + so + 6);

        unsigned ovf = (c & OVF) ? 1u : 0u;
        unsigned tot = ovf ? 0u : c;
        #pragma unroll
        for (int o = 32; o >= 1; o >>= 1) {
            tot += __shfl_xor(tot, o);
            ovf |= __shfl_xor(ovf, o);
        }

        if (!ovf && tot >= 9) {
            if (c >= 1) insertChain(e, q01.x);
            if (c >= 2) insertChain(e, q01.y);
            if (c >= 3) insertChain(e, q23.x);
            if (c >= 4) insertChain(e, q23.y);
            if (c >= 5) insertChain(e, q45.x);
            if (c >= 6) insertChain(e, q45.y);
            if (c >= 7) insertChain(e, q67.x);
            if (c >= 8) insertChain(e, q67.y);
            for (unsigned s = 8; s < c; s++)       // tail: P(c>8 | lambda 3.8) tiny
                insertChain(e, l1[so + s]);
        } else {
            scanRange(anchors, c_lvl_start[1], c_lvl_end[1], lane, gx, gy, gz, sg, e);
        }
        waveTop9(e, lane, &cands[9]);
    } else {
        // lvl0 gather: 8 segments/lane, entries[0..3] prefetched unconditionally
        size_t sb = (size_t)g * SEG0 * QCAP;
        unsigned cs[8];
        ulonglong2 p01[8], p23[8];
        #pragma unroll
        for (int j = 0; j < 8; j++)
            cs[j] = c0[(size_t)g * SEG0 + lane + 64*j];
        #pragma unroll
        for (int j = 0; j < 8; j++) {
            size_t so = sb + (size_t)(lane + 64*j) * QCAP;
            p01[j] = *(const ulonglong2*)(l0 + so);
            p23[j] = *(const ulonglong2*)(l0 + so + 2);
        }

        unsigned tot = 0, ovf = 0;
        #pragma unroll
        for (int j = 0; j < 8; j++) {
            if (cs[j] & OVF) ovf = 1; else tot += cs[j];
        }
        #pragma unroll
        for (int o = 32; o >= 1; o >>= 1) {
            tot += __shfl_xor(tot, o);
            ovf |= __shfl_xor(ovf, o);
        }

        if (!ovf && tot >= 9) {
            #pragma unroll
            for (int j = 0; j < 8; j++) {
                unsigned c = cs[j];
                if (c >= 1) insertChain(e, p01[j].x);
                if (c >= 2) insertChain(e, p01[j].y);
                if (c >= 3) insertChain(e, p23[j].x);
                if (c >= 4) insertChain(e, p23[j].y);
                if (c > 4) {                        // tail: P(c>4 | lambda 0.5) tiny
                    size_t so = sb + (size_t)(lane + 64*j) * QCAP;
                    for (unsigned s = 4; s < c; s++)
                        insertChain(e, l0[so + s]);
                }
            }
        } else {
            scanRange(anchors, c_lvl_start[0], c_lvl_end[0], lane, gx, gy, gz, sg, e);
        }
        waveTop9(e, lane, &cands[0]);
    }
    __syncthreads();

    // merge the two lvl2 half top-9s (18 candidates, 1 per lane) exactly
    if (wl == 2) {
        unsigned long long v = (lane < 18) ? cand2[lane] : ~0ULL;
        #pragma unroll
        for (int r9 = 0; r9 < 9; r9++) {
            unsigned long long mn = v;
            #pragma unroll
            for (int off = 32; off >= 1; off >>= 1) {
                unsigned long long o = __shfl_xor(mn, off);
                mn = (o < mn) ? o : mn;
            }
            if (lane == 0) cands[18 + r9] = mn;
            v = (v == mn) ? ~0ULL : v;
        }
    }
    __syncthreads();

    if (tid < 64) {
        float vg = (gx2 - gx1) * (gy2 - gy1) * (gz2 - gz1);
        bool valid = (tid < NCAND);
        float iou = 0.0f;
        int aidx = 0;
        float acx = 0.0f, acy = 0.0f, acz = 0.0f;
        if (valid) {
            aidx = (int)(unsigned)cands[tid];
            float ax1 = anchors[aidx*6+0], ay1 = anchors[aidx*6+1];
            float ax2 = anchors[aidx*6+2], ay2 = anchors[aidx*6+3];
            float az1 = anchors[aidx*6+4], az2 = anchors[aidx*6+5];
            float va = (ax2 - ax1) * (ay2 - ay1) * (az2 - az1);
            float wx = fmaxf(fminf(ax2, gx2) - fmaxf(ax1, gx1), 0.0f);
            float wy = fmaxf(fminf(ay2, gy2) - fmaxf(ay1, gy1), 0.0f);
            float wz = fmaxf(fminf(az2, gz2) - fmaxf(az1, gz1), 0.0f);
            float inter = wx * wy * wz;
            iou = inter / (va + vg - inter + 1e-6f);
            acx = (ax1 + ax2) * 0.5f;
            acy = (ay1 + ay2) * 0.5f;
            acz = (az1 + az2) * 0.5f;
        }

        float s = iou;
        #pragma unroll
        for (int o = 32; o >= 1; o >>= 1) s += __shfl_xor(s, o);
        float mean = s / 36.0f;
        float dev = valid ? (iou - mean) : 0.0f;
        float s2 = dev * dev;
        #pragma unroll
        for (int o = 32; o >= 1; o >>= 1) s2 += __shfl_xor(s2, o);
        float thr = fmaxf(mean + sqrtf(s2 / 35.0f), 0.0f);  // MIN_IOU = 0

        if (valid && iou >= thr) {
            bool inside = (acx >= gx1) & (acx <= gx2) &
                          (acy >= gy1) & (acy <= gy2) &
                          (acz >= gz1) & (acz <= gz2);
            if (inside) {
                unsigned long long p =
                    ((unsigned long long)__float_as_uint(iou) << 32) | (unsigned)(~(unsigned)g);
                atomicMax(&packed[aidx], p);
            }
        }
    }
}

__global__ void phaseD(const unsigned long long* __restrict__ packed,
                       float* __restrict__ out, int n) {
    int i = blockIdx.x * blockDim.x + threadIdx.x;
    if (i >= n) return;
    unsigned long long p = packed[i];
    float gt_f, iou_f, lab_f;
    if (p == 0ULL) {
        gt_f = -1.0f; iou_f = 0.0f; lab_f = 0.0f;
    } else {
        unsigned low = (unsigned)p;
        int gidx = (int)(~low);
        iou_f = __uint_as_float((unsigned)(p >> 32));
        gt_f = (float)gidx;
        lab_f = 1.0f;
    }
    out[i]       = gt_f;
    out[n + i]   = iou_f;
    out[2*n + i] = lab_f;
}

extern "C" void kernel_launch(void* const* d_in, const int* in_sizes, int n_in,
                              void* d_out, int out_size, void* d_ws, size_t ws_size,
                              hipStream_t stream) {
    const float* gt      = (const float*)d_in[0];
    const float* anchors = (const float*)d_in[1];
    int m = in_sizes[0] / 6;   // 64
    int n = in_sizes[1] / 6;   // 299520

    char* ws = (char*)d_ws;
    unsigned long long* packed = (unsigned long long*)ws;                    // n*8
    size_t off = (size_t)n * 8;
    unsigned long long* l0 = (unsigned long long*)(ws + off);                // 64*512*64*8 = 16 MiB
    off += (size_t)64 * SEG0 * QCAP * 8;
    unsigned long long* l1 = (unsigned long long*)(ws + off);                // 64*64*64*8 = 2 MiB
    off += (size_t)64 * SEG1 * QCAP * 8;
    unsigned* c0 = (unsigned*)(ws + off);                                    // 64*512*4
    off += (size_t)64 * SEG0 * 4;
    unsigned* c1 = (unsigned*)(ws + off);                                    // 64*64*4
    off += (size_t)64 * SEG1 * 4;
    float4* c4 = (float4*)(ws + off);                                        // 4608*16
    float* out = (float*)d_out;

    scanK<<<SEG0 + SEG1 + C4BLOCKS, 256, 0, stream>>>(anchors, gt, l0, l1, c0, c1,
                                                      packed, c4, n, m);
    selectC<<<m, 256, 0, stream>>>(l0, l1, c0, c1, anchors, gt, c4, packed, n);
    phaseD<<<(n + 255) / 256, 256, 0, stream>>>(packed, out, n);
}